// Round 1
// baseline (151.601 us; speedup 1.0000x reference)
//
#include <hip/hip_runtime.h>
#include <hip/hip_bf16.h>
#include <cstdint>

#define K_DIM 768
#define M_DIM 3072
#define BS_TOTAL 16384  // B * S = 8 * 2048

typedef __attribute__((ext_vector_type(4))) float f32x4;
typedef __attribute__((ext_vector_type(8))) short bf16x8;
typedef __attribute__((ext_vector_type(4))) unsigned short u16x4;
typedef __attribute__((ext_vector_type(4))) float fv4;

typedef unsigned int u32_g __attribute__((address_space(1)));
typedef unsigned int u32_l __attribute__((address_space(3)));

static __device__ __forceinline__ void async_load16(const void* g, void* l) {
    __builtin_amdgcn_global_load_lds((const u32_g*)g, (u32_l*)l, 16, 0, 0);
}

static __device__ __forceinline__ unsigned short f2bf(float f) {
    unsigned u = __builtin_bit_cast(unsigned, f);
    u += 0x7fffu + ((u >> 16) & 1u);   // round-to-nearest-even
    return (unsigned short)(u >> 16);
}

// One block per row: zero the dense bf16 row, then scatter CSR nonzeros.
__global__ void densify_kernel(const float* __restrict__ values,
                               const int* __restrict__ row_offsets,
                               const int* __restrict__ column_indices,
                               unsigned short* __restrict__ Wb) {
    const int r = blockIdx.x;
    const int t = threadIdx.x;
    unsigned int* wrow32 = (unsigned int*)(Wb + (size_t)r * K_DIM);
    for (int i = t; i < K_DIM / 2; i += 256) wrow32[i] = 0u;
    __syncthreads();
    const int start = row_offsets[r], end = row_offsets[r + 1];
    unsigned short* wrow = Wb + (size_t)r * K_DIM;
    for (int i = start + t; i < end; i += 256)
        wrow[column_indices[i]] = f2bf(values[i]);
}

// fp32 -> bf16, 4 elements/thread
__global__ void convert_x_kernel(const float* __restrict__ x,
                                 unsigned short* __restrict__ xb, int n4) {
    int i = blockIdx.x * 256 + threadIdx.x;
    if (i < n4) {
        fv4 v = ((const fv4*)x)[i];
        u16x4 o;
        o[0] = f2bf(v[0]); o[1] = f2bf(v[1]); o[2] = f2bf(v[2]); o[3] = f2bf(v[3]);
        ((u16x4*)xb)[i] = o;
    }
}

// C[16384,3072] = X[16384,768] * W[3072,768]^T + bias
// 128x128 tile, BK=64, 4 waves (2x2), 16x16x32 bf16 MFMA (m97 structure)
__global__ __launch_bounds__(256) void gemm_kernel(
    const unsigned short* __restrict__ X,
    const unsigned short* __restrict__ W,
    const float* __restrict__ bias,
    float* __restrict__ out) {
    __shared__ __align__(16) unsigned short As[128 * 64];
    __shared__ __align__(16) unsigned short Bs[128 * 64];

    // XCD-aware swizzle: nwg = 3072, divisible by 8
    const int nwg = gridDim.x;
    const int cpx = nwg >> 3;
    int bid = blockIdx.x;
    bid = (bid & 7) * cpx + (bid >> 3);
    const int bx = bid % (M_DIM / 128);   // 24 tiles along m
    const int by = bid / (M_DIM / 128);   // 128 tiles along bs
    const int row0 = by * 128;
    const int col0 = bx * 128;

    const int t = threadIdx.x;
    const int lane = t & 63;
    const int wave = t >> 6;
    const int wr = (wave >> 1) * 64;   // wave row offset in tile
    const int wc = (wave & 1) * 64;    // wave col offset in tile

    const int fr = lane & 15;          // fragment row/col
    const int fk = (lane >> 4) * 8;    // fragment k offset

    f32x4 acc[4][4] = {};

    for (int kt = 0; kt < K_DIM; kt += 64) {
#pragma unroll
        for (int j = 0; j < 4; ++j) {
            const int u = j * 256 + t;            // 0..1023
            const int row = u >> 3;               // 0..127
            const int seg = (u & 7) * 8;          // element offset in row
            async_load16(X + (size_t)(row0 + row) * K_DIM + kt + seg, As + u * 8);
        }
#pragma unroll
        for (int j = 0; j < 4; ++j) {
            const int u = j * 256 + t;
            const int row = u >> 3;
            const int seg = (u & 7) * 8;
            async_load16(W + (size_t)(col0 + row) * K_DIM + kt + seg, Bs + u * 8);
        }
        __syncthreads();

#pragma unroll
        for (int ks = 0; ks < 2; ++ks) {
            bf16x8 a[4], b[4];
#pragma unroll
            for (int i = 0; i < 4; ++i)
                a[i] = *(const bf16x8*)(As + (wr + i * 16 + fr) * 64 + ks * 32 + fk);
#pragma unroll
            for (int i = 0; i < 4; ++i)
                b[i] = *(const bf16x8*)(Bs + (wc + i * 16 + fr) * 64 + ks * 32 + fk);
#pragma unroll
            for (int mi = 0; mi < 4; ++mi)
#pragma unroll
                for (int ni = 0; ni < 4; ++ni)
                    acc[mi][ni] = __builtin_amdgcn_mfma_f32_16x16x32_bf16(
                        a[mi], b[ni], acc[mi][ni], 0, 0, 0);
        }
        __syncthreads();
    }

    // epilogue: D row = (lane>>4)*4 + j, col = lane&15 (m89-verified layout)
    float bv[4];
#pragma unroll
    for (int ni = 0; ni < 4; ++ni) bv[ni] = bias[col0 + wc + ni * 16 + fr];

    const int orow0 = row0 + wr + (lane >> 4) * 4;
#pragma unroll
    for (int mi = 0; mi < 4; ++mi)
#pragma unroll
        for (int j = 0; j < 4; ++j) {
            float* op = out + (size_t)(orow0 + mi * 16 + j) * M_DIM + col0 + wc + fr;
#pragma unroll
            for (int ni = 0; ni < 4; ++ni)
                op[ni * 16] = acc[mi][ni][j] + bv[ni];
        }
}

extern "C" void kernel_launch(void* const* d_in, const int* in_sizes, int n_in,
                              void* d_out, int out_size, void* d_ws, size_t ws_size,
                              hipStream_t stream) {
    const float* values         = (const float*)d_in[0];
    const float* bias           = (const float*)d_in[1];
    const float* x              = (const float*)d_in[2];
    const int*   row_offsets    = (const int*)d_in[4];
    const int*   column_indices = (const int*)d_in[5];

    unsigned short* Wb = (unsigned short*)d_ws;                                  // 3072*768 bf16
    unsigned short* Xb = (unsigned short*)((char*)d_ws + (size_t)M_DIM * K_DIM * 2); // 16384*768 bf16

    densify_kernel<<<M_DIM, 256, 0, stream>>>(values, row_offsets, column_indices, Wb);

    const int n4 = BS_TOTAL * K_DIM / 4;
    convert_x_kernel<<<(n4 + 255) / 256, 256, 0, stream>>>(x, Xb, n4);

    const int grid = (BS_TOTAL / 128) * (M_DIM / 128);  // 128 * 24 = 3072
    gemm_kernel<<<grid, 256, 0, stream>>>(Xb, Wb, bias, (float*)d_out);
}

// Round 2
// 109.543 us; speedup vs baseline: 1.3839x; 1.3839x over previous
//
#include <hip/hip_runtime.h>
#include <hip/hip_bf16.h>
#include <cstdint>

#define K_DIM 768
#define M_DIM 3072
#define BS_TOTAL 16384  // B * S
#define KT 12           // K tiles of 64

typedef __attribute__((ext_vector_type(4))) float f32x4;
typedef __attribute__((ext_vector_type(8))) short bf16x8;
typedef __attribute__((ext_vector_type(4))) unsigned short u16x4;
typedef __attribute__((ext_vector_type(4))) float fv4;

typedef unsigned int u32_g __attribute__((address_space(1)));
typedef unsigned int u32_l __attribute__((address_space(3)));

static __device__ __forceinline__ void async_load16(const void* g, void* l) {
    __builtin_amdgcn_global_load_lds((const u32_g*)g, (u32_l*)l, 16, 0, 0);
}

#define BAR() __builtin_amdgcn_s_barrier()
#define SCHEDB() __builtin_amdgcn_sched_barrier(0)

static __device__ __forceinline__ unsigned short f2bf(float f) {
    unsigned u = __builtin_bit_cast(unsigned, f);
    u += 0x7fffu + ((u >> 16) & 1u);   // RNE
    return (unsigned short)(u >> 16);
}

__global__ void densify_kernel(const float* __restrict__ values,
                               const int* __restrict__ row_offsets,
                               const int* __restrict__ column_indices,
                               unsigned short* __restrict__ Wb) {
    const int r = blockIdx.x;
    const int t = threadIdx.x;
    unsigned int* wrow32 = (unsigned int*)(Wb + (size_t)r * K_DIM);
    for (int i = t; i < K_DIM / 2; i += 256) wrow32[i] = 0u;
    __syncthreads();
    const int start = row_offsets[r], end = row_offsets[r + 1];
    unsigned short* wrow = Wb + (size_t)r * K_DIM;
    for (int i = start + t; i < end; i += 256)
        wrow[column_indices[i]] = f2bf(values[i]);
}

__global__ void convert_x_kernel(const float* __restrict__ x,
                                 unsigned short* __restrict__ xb, int n4) {
    int i = blockIdx.x * 256 + threadIdx.x;
    if (i < n4) {
        fv4 v = ((const fv4*)x)[i];
        u16x4 o;
        o[0] = f2bf(v[0]); o[1] = f2bf(v[1]); o[2] = f2bf(v[2]); o[3] = f2bf(v[3]);
        ((u16x4*)xb)[i] = o;
    }
}

// ---- 256x256 tile, BK=64, 8 waves (2Mx4N), 8-phase schedule, counted vmcnt ----
// LDS: sm[buf][A/B][256*64] bf16, 128 KiB total, double-buffered per K-tile.
// Swizzle: elem col ^= (row&7)<<3, applied on the GLOBAL source (inverse) for the
// linear global_load_lds dest, and on every ds_read address (rule 21).

#define STAGE_A(buf, t, half)                                                   \
    { _Pragma("unroll") for (int c = 0; c < 2; ++c) {                           \
        const int u = c * 512 + tid;                                            \
        const int row = (half) * 128 + (u >> 3);                                \
        const int gs = (u & 7) ^ (row & 7);                                     \
        async_load16(X + (size_t)(row0 + row) * K_DIM + (t) * 64 + gs * 8,      \
                     &sm[buf][0][row * 64 + (u & 7) * 8]); } }

#define STAGE_B(buf, t, half)                                                   \
    { _Pragma("unroll") for (int c = 0; c < 2; ++c) {                           \
        const int u = c * 512 + tid;                                            \
        const int row = (half) * 128 + (u >> 3);                                \
        const int gs = (u & 7) ^ (row & 7);                                     \
        async_load16(W + (size_t)(col0 + row) * K_DIM + (t) * 64 + gs * 8,      \
                     &sm[buf][1][row * 64 + (u & 7) * 8]); } }

#define LDA(buf, mh)                                                            \
    { _Pragma("unroll") for (int mi = 0; mi < 4; ++mi) {                        \
        const int row = wm * 128 + (mh) * 64 + mi * 16 + fr;                    \
        const int sw = (row & 7) << 3;                                          \
        aq[mi][0] = *(const bf16x8*)&sm[buf][0][row * 64 + ((kq * 8) ^ sw)];    \
        aq[mi][1] = *(const bf16x8*)&sm[buf][0][row * 64 + ((32 + kq * 8) ^ sw)]; } }

#define LDB(buf, nh, breg)                                                      \
    { _Pragma("unroll") for (int ni = 0; ni < 2; ++ni) {                        \
        const int row = wn * 64 + (nh) * 32 + ni * 16 + fr;                     \
        const int sw = (row & 7) << 3;                                          \
        breg[ni][0] = *(const bf16x8*)&sm[buf][1][row * 64 + ((kq * 8) ^ sw)];  \
        breg[ni][1] = *(const bf16x8*)&sm[buf][1][row * 64 + ((32 + kq * 8) ^ sw)]; } }

#define MFMA16(mh, nh, breg)                                                    \
    { __builtin_amdgcn_s_setprio(1);                                            \
      _Pragma("unroll") for (int mi = 0; mi < 4; ++mi)                          \
      _Pragma("unroll") for (int ni = 0; ni < 2; ++ni) {                        \
        acc[(mh)*4+mi][(nh)*2+ni] = __builtin_amdgcn_mfma_f32_16x16x32_bf16(    \
            aq[mi][0], breg[ni][0], acc[(mh)*4+mi][(nh)*2+ni], 0, 0, 0);        \
        acc[(mh)*4+mi][(nh)*2+ni] = __builtin_amdgcn_mfma_f32_16x16x32_bf16(    \
            aq[mi][1], breg[ni][1], acc[(mh)*4+mi][(nh)*2+ni], 0, 0, 0); }      \
      __builtin_amdgcn_s_setprio(0); }

__global__ __launch_bounds__(512, 2) void gemm_kernel(
    const unsigned short* __restrict__ X,
    const unsigned short* __restrict__ W,
    const float* __restrict__ bias,
    float* __restrict__ out) {
    __shared__ __align__(16) unsigned short sm[2][2][256 * 64];  // 128 KiB

    // XCD-aware bijective swizzle: nwg = 768, divisible by 8
    const int nwg = gridDim.x;
    int bid = blockIdx.x;
    bid = (bid & 7) * (nwg >> 3) + (bid >> 3);
    const int bx = bid % (M_DIM / 256);   // 12 col tiles
    const int by = bid / (M_DIM / 256);   // 64 row tiles
    const int row0 = by * 256;
    const int col0 = bx * 256;

    const int tid  = threadIdx.x;
    const int lane = tid & 63;
    const int wave = tid >> 6;
    const int wm = wave >> 2;   // 0..1 -> A rows wm*128..+127
    const int wn = wave & 3;    // 0..3 -> B rows wn*64..+63
    const int fr = lane & 15;
    const int kq = lane >> 4;   // 0..3

    f32x4 acc[8][4] = {};
    bf16x8 aq[4][2], b0[2][2], b1[2][2];

    // prologue: tile 0 fully + B of tile 1 (A of tile 1 staged in t=0 P0/P1)
    STAGE_A(0, 0, 0); STAGE_A(0, 0, 1);
    STAGE_B(0, 0, 0); STAGE_B(0, 0, 1);
    STAGE_B(1, 1, 0); STAGE_B(1, 1, 1);
    asm volatile("s_waitcnt vmcnt(4)" ::: "memory");  // tile 0 complete; B(1) may fly
    SCHEDB();
    BAR();

    for (int t = 0; t < KT; ++t) {
        const int buf = t & 1, nbuf = buf ^ 1;
        // ---- P0: quadrant (mh0, nh0) ----
        LDA(buf, 0);
        LDB(buf, 0, b0);
        if (t + 1 < KT) STAGE_A(nbuf, t + 1, 0);
        BAR();
        MFMA16(0, 0, b0);
        BAR();
        // ---- P1: (mh0, nh1) ----
        LDB(buf, 1, b1);
        if (t + 1 < KT) STAGE_A(nbuf, t + 1, 1);
        BAR();
        MFMA16(0, 1, b1);
        BAR();
        // ---- P2: (mh1, nh1) ----
        LDA(buf, 1);
        if (t + 2 < KT) STAGE_B(buf, t + 2, 0);
        BAR();
        MFMA16(1, 1, b1);
        BAR();
        // ---- P3: (mh1, nh0) ----
        if (t + 2 < KT) STAGE_B(buf, t + 2, 1);
        BAR();
        MFMA16(1, 0, b0);
        // counted wait, once per K-tile; never 0 in steady state
        if (t + 2 < KT)      { asm volatile("s_waitcnt vmcnt(4)" ::: "memory"); SCHEDB(); }
        else if (t + 1 < KT) { asm volatile("s_waitcnt vmcnt(0)" ::: "memory"); SCHEDB(); }
        BAR();
    }

    // epilogue: frag row = kq*4 + j, col = fr (m89-verified C/D layout)
    float bv[4];
#pragma unroll
    for (int ni = 0; ni < 4; ++ni) bv[ni] = bias[col0 + wn * 64 + ni * 16 + fr];

    const int orow0 = row0 + wm * 128 + kq * 4;
#pragma unroll
    for (int mi = 0; mi < 8; ++mi)
#pragma unroll
        for (int j = 0; j < 4; ++j) {
            float* op = out + (size_t)(orow0 + mi * 16 + j) * M_DIM + col0 + wn * 64 + fr;
#pragma unroll
            for (int ni = 0; ni < 4; ++ni)
                op[ni * 16] = acc[mi][ni][j] + bv[ni];
        }
}

extern "C" void kernel_launch(void* const* d_in, const int* in_sizes, int n_in,
                              void* d_out, int out_size, void* d_ws, size_t ws_size,
                              hipStream_t stream) {
    const float* values         = (const float*)d_in[0];
    const float* bias           = (const float*)d_in[1];
    const float* x              = (const float*)d_in[2];
    const int*   row_offsets    = (const int*)d_in[4];
    const int*   column_indices = (const int*)d_in[5];

    unsigned short* Wb = (unsigned short*)d_ws;
    unsigned short* Xb = (unsigned short*)((char*)d_ws + (size_t)M_DIM * K_DIM * 2);

    densify_kernel<<<M_DIM, 256, 0, stream>>>(values, row_offsets, column_indices, Wb);

    const int n4 = BS_TOTAL * K_DIM / 4;
    convert_x_kernel<<<(n4 + 255) / 256, 256, 0, stream>>>(x, Xb, n4);

    const int grid = (BS_TOTAL / 256) * (M_DIM / 256);  // 64 * 12 = 768
    gemm_kernel<<<grid, 512, 0, stream>>>(Xb, Wb, bias, (float*)d_out);
}